// Round 9
// baseline (519.110 us; speedup 1.0000x reference)
//
#include <hip/hip_runtime.h>

#define N_NODES 100000
#define N_EDGES 640000
#define D 128
#define SCAN_TILE 1024
#define SCAN_BLOCKS ((N_NODES + SCAN_TILE - 1) / SCAN_TILE)  // 98

typedef __attribute__((ext_vector_type(8))) short bf16x8;   // 8 bf16 = 4 VGPRs
typedef __attribute__((ext_vector_type(4))) float f32x4;

__device__ __forceinline__ unsigned short f32_to_bf16(float f) {
  union { float f; unsigned int u; } v; v.f = f;
  unsigned int u = v.u;
  unsigned int r = (u + 0x7fffu + ((u >> 16) & 1u)) >> 16;  // RNE
  return (unsigned short)r;
}
__device__ __forceinline__ float bf16_lo(unsigned int u) { return __uint_as_float(u << 16); }
__device__ __forceinline__ float bf16_hi(unsigned int u) { return __uint_as_float(u & 0xffff0000u); }

__device__ __forceinline__ void acc8(float* a, uint4 r) {
  a[0] += bf16_lo(r.x); a[1] += bf16_hi(r.x);
  a[2] += bf16_lo(r.y); a[3] += bf16_hi(r.y);
  a[4] += bf16_lo(r.z); a[5] += bf16_hi(r.z);
  a[6] += bf16_lo(r.w); a[7] += bf16_hi(r.w);
}

// ---------------------------------------------------------------- utilities
__global__ void zero_i32(int* __restrict__ p, int n) {
  int i = blockIdx.x * blockDim.x + threadIdx.x;
  if (i < n) p[i] = 0;
}

__global__ void f32_to_bf16_vec(const float* __restrict__ in, unsigned short* __restrict__ out, int n4) {
  int i = blockIdx.x * blockDim.x + threadIdx.x;
  if (i < n4) {
    float4 v = ((const float4*)in)[i];
    ushort4 o;
    o.x = f32_to_bf16(v.x); o.y = f32_to_bf16(v.y);
    o.z = f32_to_bf16(v.z); o.w = f32_to_bf16(v.w);
    ((ushort4*)out)[i] = o;
  }
}

// 8 weight matrices [128x128] fp32 row-major [k][n] -> bf16 transposed Wt[n][k]
__global__ void transpose_w(const float* __restrict__ W0, const float* __restrict__ W1,
                            const float* __restrict__ W2, const float* __restrict__ W3,
                            const float* __restrict__ W4, const float* __restrict__ W5,
                            const float* __restrict__ W6, const float* __restrict__ W7,
                            unsigned short* __restrict__ wt) {
  int id = blockIdx.x * 256 + threadIdx.x;  // 512 blocks x 256 = 131072
  int mat = id >> 14;
  int rem = id & 16383;
  int n = rem >> 7, k = rem & 127;
  const float* Wm = mat < 4 ? (mat < 2 ? (mat == 0 ? W0 : W1) : (mat == 2 ? W2 : W3))
                            : (mat < 6 ? (mat == 4 ? W4 : W5) : (mat == 6 ? W6 : W7));
  wt[id] = f32_to_bf16(Wm[k * D + n]);
}

// ------------------------------------------------------------- CSR building (pos edges only)
__global__ void hist_kernel(const int* __restrict__ dst, int* __restrict__ deg, int E) {
  int i = blockIdx.x * blockDim.x + threadIdx.x;
  if (i < E) atomicAdd(&deg[dst[i]], 1);
}

__global__ void scan_blocksum(const int* __restrict__ deg, int* __restrict__ partial, int n) {
  __shared__ int lds[256];
  const int tid = threadIdx.x;
  const int base = blockIdx.x * SCAN_TILE + tid * 4;
  int s = 0;
#pragma unroll
  for (int j = 0; j < 4; ++j) {
    int i = base + j;
    if (i < n) s += deg[i];
  }
  lds[tid] = s;
  __syncthreads();
  for (int off = 128; off > 0; off >>= 1) {
    if (tid < off) lds[tid] += lds[tid + off];
    __syncthreads();
  }
  if (tid == 0) partial[blockIdx.x] = lds[0];
}

__global__ void scan_offsets(int* __restrict__ partial, int* __restrict__ row_start, int nb, int n) {
  __shared__ int lds[128];
  const int tid = threadIdx.x;
  int v = (tid < nb) ? partial[tid] : 0;
  lds[tid] = v;
  __syncthreads();
  for (int off = 1; off < 128; off <<= 1) {
    int t = (tid >= off) ? lds[tid - off] : 0;
    __syncthreads();
    lds[tid] += t;
    __syncthreads();
  }
  if (tid < nb) partial[tid] = (tid == 0) ? 0 : lds[tid - 1];
  if (tid == 0) row_start[n] = lds[nb - 1];
}

__global__ void scan_final(const int* __restrict__ deg, const int* __restrict__ partial,
                           int* __restrict__ row_start, int n) {
  __shared__ int lds[256];
  const int tid = threadIdx.x;
  const int base = blockIdx.x * SCAN_TILE + tid * 4;
  int d[4];
  int s = 0;
#pragma unroll
  for (int j = 0; j < 4; ++j) {
    int i = base + j;
    d[j] = (i < n) ? deg[i] : 0;
    s += d[j];
  }
  lds[tid] = s;
  __syncthreads();
  for (int off = 1; off < 256; off <<= 1) {
    int t = (tid >= off) ? lds[tid - off] : 0;
    __syncthreads();
    lds[tid] += t;
    __syncthreads();
  }
  int pre = partial[blockIdx.x] + lds[tid] - s;
#pragma unroll
  for (int j = 0; j < 4; ++j) {
    int i = base + j;
    if (i < n) {
      row_start[i] = pre;
      pre += d[j];
    }
  }
}

__global__ void fill_kernel(const int* __restrict__ src, const int* __restrict__ dst,
                            const int* __restrict__ row_start, int* __restrict__ cursor,
                            int* __restrict__ esrc, int E) {
  int i = blockIdx.x * blockDim.x + threadIdx.x;
  if (i < E) {
    int d = dst[i];
    int pos = atomicAdd(&cursor[d], 1);
    esrc[row_start[d] + pos] = src[i];
  }
}

// ----------------------------------------------------- gather-only mean kernel
// One node per 16-lane group, 16 nodes per 256-thread block -> 6250 blocks.
// No LDS, no MFMA, low VGPR: occupancy-driven TLP is the latency hiding.
// Writes mean bf16 coalesced.
__global__ __launch_bounds__(256) void gather_mean(
    const unsigned short* __restrict__ hin,
    const int* __restrict__ row_start, const int* __restrict__ esrc,
    unsigned short* __restrict__ mean, int M) {
  const int t = blockIdx.x * blockDim.x + threadIdx.x;
  const int node = t >> 4;
  const int fl = t & 15;  // 16 B of the row per lane
  if (node >= M) return;
  const int s0 = row_start[node], s1 = row_start[node + 1];
  float ac[8] = {0.f, 0.f, 0.f, 0.f, 0.f, 0.f, 0.f, 0.f};
  int e = s0;
  for (; e + 4 <= s1; e += 4) {
    int i0 = esrc[e], i1 = esrc[e + 1], i2 = esrc[e + 2], i3 = esrc[e + 3];
    uint4 r0 = *(const uint4*)(hin + (((size_t)i0) << 7) + fl * 8);
    uint4 r1 = *(const uint4*)(hin + (((size_t)i1) << 7) + fl * 8);
    uint4 r2 = *(const uint4*)(hin + (((size_t)i2) << 7) + fl * 8);
    uint4 r3 = *(const uint4*)(hin + (((size_t)i3) << 7) + fl * 8);
    acc8(ac, r0); acc8(ac, r1); acc8(ac, r2); acc8(ac, r3);
  }
  for (; e < s1; ++e) {
    uint4 r0 = *(const uint4*)(hin + (((size_t)esrc[e]) << 7) + fl * 8);
    acc8(ac, r0);
  }
  const float inv = 1.0f / (float)max(s1 - s0, 1);
#pragma unroll
  for (int k = 0; k < 8; ++k) ac[k] *= inv;
  uint4 o;
  o.x = (unsigned)f32_to_bf16(ac[0]) | ((unsigned)f32_to_bf16(ac[1]) << 16);
  o.y = (unsigned)f32_to_bf16(ac[2]) | ((unsigned)f32_to_bf16(ac[3]) << 16);
  o.z = (unsigned)f32_to_bf16(ac[4]) | ((unsigned)f32_to_bf16(ac[5]) << 16);
  o.w = (unsigned)f32_to_bf16(ac[6]) | ((unsigned)f32_to_bf16(ac[7]) << 16);
  *reinterpret_cast<uint4*>(mean + (((size_t)node) << 7) + fl * 8) = o;
}

// ----------------------------------------------------- persistent-weight layer (layers 1 & 2)
// ROUNDS 5-8 LESSON: four per-tile variants all landed 40-48us; the invariant
// cost is the 8-stage x 2-barrier weight chain paid per SHORT-LIVED block.
// Fix: 256 blocks x 512 threads, each block stages BOTH full weight matrices
// into LDS ONCE (69.6 KB) + 8 per-wave epilogue tiles (34.8 KB) = 104 KB,
// ONE barrier total. Then each of the 8 waves independently walks 16-row
// chunks (6250 chunks / 2048 wave-streams): prefetch next chunk's A-frags ->
// 64 MFMAs from resident LDS -> per-wave private epilogue transpose (own
// tile, same-wave lgkm ordering). ZERO barriers in the loop; weights read
// from HBM/L2 once per CU instead of 8 panels per 64-node block.
__global__ __launch_bounds__(512, 1) void layer_persist(
    const unsigned short* __restrict__ hin,
    const unsigned short* __restrict__ mean,
    const unsigned short* __restrict__ Wts, const unsigned short* __restrict__ Wtn,
    const float* __restrict__ bias,
    unsigned short* __restrict__ out0, int M, int C) {
  __shared__ unsigned short ws[128][136];   // 34.8 KB full Ws^T
  __shared__ unsigned short wn[128][136];   // 34.8 KB full Wn^T
  __shared__ unsigned short et[8][16][136]; // 34.8 KB per-wave epilogue tiles
  const int tid = threadIdx.x;
  const int wave = tid >> 6;
  const int lane = tid & 63;
  const int row = lane & 15;
  const int q = lane >> 4;

  // stage both full matrices: 2048 16B-chunks each, 512 threads -> 4 iters
#pragma unroll
  for (int i = 0; i < 4; ++i) {
    int seg = i * 512 + tid;
    int r = seg >> 4, o = (seg & 15) * 8;
    *reinterpret_cast<bf16x8*>(&ws[r][o]) = *reinterpret_cast<const bf16x8*>(Wts + r * D + o);
    *reinterpret_cast<bf16x8*>(&wn[r][o]) = *reinterpret_cast<const bf16x8*>(Wtn + r * D + o);
  }
  // bias fragments (chunk-invariant): bv[t] pairs with output col t*16+row
  float bv[8];
#pragma unroll
  for (int t = 0; t < 8; ++t) bv[t] = bias[t * 16 + row];
  __syncthreads();  // the ONLY barrier

  auto ldfr = [&](const unsigned short* p, int mload, bf16x8* f) {
#pragma unroll
    for (int s = 0; s < 4; ++s)
      f[s] = *reinterpret_cast<const bf16x8*>(p + (size_t)mload * D + s * 32 + q * 8);
  };

  int c = blockIdx.x * 8 + wave;  // wave-stream id, stride 2048
  if (c >= C) return;
  bf16x8 ah[4], am[4], nh[4], nm[4];
  ldfr(hin, min(c * 16 + row, M - 1), ah);
  ldfr(mean, min(c * 16 + row, M - 1), am);

  while (true) {
    const int cn = c + 2048;
    if (cn < C) {  // prefetch next chunk under this chunk's MFMAs
      ldfr(hin, min(cn * 16 + row, M - 1), nh);
      ldfr(mean, min(cn * 16 + row, M - 1), nm);
    }
    f32x4 acc[8];
#pragma unroll
    for (int t = 0; t < 8; ++t) acc[t] = (f32x4){0.f, 0.f, 0.f, 0.f};
#pragma unroll
    for (int s = 0; s < 4; ++s)
#pragma unroll
      for (int t = 0; t < 8; ++t)
        acc[t] = __builtin_amdgcn_mfma_f32_16x16x32_bf16(
            ah[s], *reinterpret_cast<const bf16x8*>(&ws[t * 16 + row][s * 32 + q * 8]), acc[t], 0, 0, 0);
#pragma unroll
    for (int s = 0; s < 4; ++s)
#pragma unroll
      for (int t = 0; t < 8; ++t)
        acc[t] = __builtin_amdgcn_mfma_f32_16x16x32_bf16(
            am[s], *reinterpret_cast<const bf16x8*>(&wn[t * 16 + row][s * 32 + q * 8]), acc[t], 0, 0, 0);
    // per-wave epilogue: acc(+bias) -> own et tile -> coalesced uint4 stores.
    // Same-wave LDS write->read ordering via compiler lgkmcnt; no barrier.
#pragma unroll
    for (int t = 0; t < 8; ++t) {
      const int col = t * 16 + row;
#pragma unroll
      for (int r2 = 0; r2 < 4; ++r2)
        et[wave][q * 4 + r2][col] = f32_to_bf16(acc[t][r2] + bv[t]);
    }
    const int m16 = c * 16;
#pragma unroll
    for (int j = 0; j < 4; ++j) {
      int k = j * 64 + lane;
      int r2 = k >> 4, c8 = (k & 15) * 8;
      int m = m16 + r2;
      if (m < M)
        *reinterpret_cast<uint4*>(out0 + (size_t)m * D + c8) =
            *reinterpret_cast<const uint4*>(&et[wave][r2][c8]);
    }
    if (cn >= C) break;
    c = cn;
#pragma unroll
    for (int s = 0; s < 4; ++s) { ah[s] = nh[s]; am[s] = nm[s]; }
  }
}

// ----------------------------------------------------- layer 3 + predictor (r8 2-tile version)
// Block = 128 nodes = 2 tiles of 64; 4 waves; wave w owns rows 16w..16w+15 of
// both tiles. h3 transits through wl own rows (same-wave ordered). Single-
// buffered panels, 17.7 KB LDS. Kept as the known-passing PRED structure.
template <bool PRED>
__global__ __launch_bounds__(256) void layer_mlp(
    const unsigned short* __restrict__ hin,
    const unsigned short* __restrict__ mean,
    const unsigned short* __restrict__ Wts, const unsigned short* __restrict__ Wtn,
    const float* __restrict__ bias,
    const unsigned short* __restrict__ WtA, const unsigned short* __restrict__ WtB,
    const float* __restrict__ biasA,
    unsigned short* __restrict__ out0, unsigned short* __restrict__ out1, int M) {
  __shared__ unsigned short wl[64][136];   // 17.4 KB: weight panel / h3 transit / epilogue tile
  const int tid = threadIdx.x;
  const int lane = tid & 63;
  const int wave = tid >> 6;
  const int m0 = blockIdx.x * 128;         // tile A at m0, tile B at m0+64
  const int row = lane & 15;
  const int q = lane >> 4;
  const int mloadA = min(m0 + wave * 16 + row, M - 1);
  const int mloadB = min(m0 + 64 + wave * 16 + row, M - 1);
  const int lrow = wave * 16 + row;        // local row 0..63

  auto stage64 = [&](const unsigned short* W, int half) {
#pragma unroll
    for (int i = 0; i < 4; ++i) {
      int seg = i * 256 + tid;
      int r = seg >> 4, o = (seg & 15) * 8;
      *reinterpret_cast<bf16x8*>(&wl[r][o]) =
          *reinterpret_cast<const bf16x8*>(W + (size_t)(half * 64 + r) * D + o);
    }
  };
  auto mfma_half = [&](bf16x8* a, f32x4* accp) {
#pragma unroll
    for (int s = 0; s < 4; ++s)
#pragma unroll
      for (int t = 0; t < 4; ++t) {
        bf16x8 b = *reinterpret_cast<const bf16x8*>(&wl[t * 16 + row][s * 32 + q * 8]);
        accp[t] = __builtin_amdgcn_mfma_f32_16x16x32_bf16(a[s], b, accp[t], 0, 0, 0);
      }
  };
  auto epilogue = [&](f32x4* accp, const float* bvec, unsigned short* dst, int base) {
    __syncthreads();
#pragma unroll
    for (int t = 0; t < 8; ++t) {
      const int col = t * 16 + row;
      const float bv = bvec ? bvec[col] : 0.f;
#pragma unroll
      for (int r = 0; r < 4; ++r)
        wl[wave * 16 + q * 4 + r][col] = f32_to_bf16(accp[t][r] + bv);
    }
    __syncthreads();
#pragma unroll
    for (int i = 0; i < 4; ++i) {
      int idx = i * 256 + tid;
      int r2 = idx >> 4;
      int c8 = (idx & 15) * 8;
      int m = base + r2;
      if (m < M)
        *reinterpret_cast<uint4*>(dst + (size_t)m * D + c8) =
            *reinterpret_cast<const uint4*>(&wl[r2][c8]);
    }
  };

  stage64(Wts, 0);
  bf16x8 ahA[4], amA[4], ahB[4], amB[4];
#pragma unroll
  for (int s = 0; s < 4; ++s) {
    ahA[s] = *reinterpret_cast<const bf16x8*>(hin + (size_t)mloadA * D + s * 32 + q * 8);
    amA[s] = *reinterpret_cast<const bf16x8*>(mean + (size_t)mloadA * D + s * 32 + q * 8);
    ahB[s] = *reinterpret_cast<const bf16x8*>(hin + (size_t)mloadB * D + s * 32 + q * 8);
    amB[s] = *reinterpret_cast<const bf16x8*>(mean + (size_t)mloadB * D + s * 32 + q * 8);
  }
  __syncthreads();

  f32x4 accA[8], accB[8];
#pragma unroll
  for (int t = 0; t < 8; ++t) { accA[t] = (f32x4){0.f, 0.f, 0.f, 0.f}; accB[t] = (f32x4){0.f, 0.f, 0.f, 0.f}; }

  mfma_half(ahA, accA); mfma_half(ahB, accB);
  __syncthreads(); stage64(Wts, 1); __syncthreads();
  mfma_half(ahA, accA + 4); mfma_half(ahB, accB + 4);
  __syncthreads(); stage64(Wtn, 0); __syncthreads();
  mfma_half(amA, accA); mfma_half(amB, accB);
  __syncthreads(); stage64(Wtn, 1); __syncthreads();
  mfma_half(amA, accA + 4); mfma_half(amB, accB + 4);

  if (!PRED) {
    epilogue(accA, bias, out0, m0);
    epilogue(accB, bias, out0, m0 + 64);
    return;
  }

  // ================= PRED tail (layer 3) =================
  __syncthreads();
  bf16x8 apA[4], apB[4];
#pragma unroll
  for (int t = 0; t < 8; ++t) {
    const int col = t * 16 + row;
    const float bv = bias[col];
#pragma unroll
    for (int r = 0; r < 4; ++r)
      wl[wave * 16 + q * 4 + r][col] = f32_to_bf16(accA[t][r] + bv);
  }
#pragma unroll
  for (int s = 0; s < 4; ++s)
    apA[s] = *reinterpret_cast<const bf16x8*>(&wl[lrow][s * 32 + q * 8]);
#pragma unroll
  for (int t = 0; t < 8; ++t) {
    const int col = t * 16 + row;
    const float bv = bias[col];
#pragma unroll
    for (int r = 0; r < 4; ++r)
      wl[wave * 16 + q * 4 + r][col] = f32_to_bf16(accB[t][r] + bv);
  }
#pragma unroll
  for (int s = 0; s < 4; ++s)
    apB[s] = *reinterpret_cast<const bf16x8*>(&wl[lrow][s * 32 + q * 8]);
  __syncthreads();

  stage64(WtA, 0);
  __syncthreads();
#pragma unroll
  for (int t = 0; t < 8; ++t) { accA[t] = (f32x4){0.f, 0.f, 0.f, 0.f}; accB[t] = (f32x4){0.f, 0.f, 0.f, 0.f}; }
  mfma_half(apA, accA); mfma_half(apB, accB);
  __syncthreads(); stage64(WtA, 1); __syncthreads();
  mfma_half(apA, accA + 4); mfma_half(apB, accB + 4);
  epilogue(accA, biasA, out0, m0);
  epilogue(accB, biasA, out0, m0 + 64);
  __syncthreads();
  stage64(WtB, 0);
  __syncthreads();
#pragma unroll
  for (int t = 0; t < 8; ++t) { accA[t] = (f32x4){0.f, 0.f, 0.f, 0.f}; accB[t] = (f32x4){0.f, 0.f, 0.f, 0.f}; }
  mfma_half(apA, accA); mfma_half(apB, accB);
  __syncthreads(); stage64(WtB, 1); __syncthreads();
  mfma_half(apA, accA + 4); mfma_half(apB, accB + 4);
  epilogue(accA, nullptr, out1, m0);
  epilogue(accB, nullptr, out1, m0 + 64);
}

// ----------------------------------------------------- edge MLP score, fused pos+neg
// score = relu(A[s]+B[d]).Wp2 + bp2 (bp1 folded into A). One dispatch for both
// edge sets (parity-interleaved groups): r8 split into two dispatches cost 93us
// vs r0's fused 86.7 -- the inter-dispatch drain/ramp outweighed the width gain.
// 4 edges / 16-lane group, 8 row-gathers in flight, int4 index loads, one
// coalesced float4 store per group.
__device__ __forceinline__ float relu_dot8(uint4 a, uint4 b, float4 w0, float4 w1) {
  return fmaxf(bf16_lo(a.x) + bf16_lo(b.x), 0.f) * w0.x +
         fmaxf(bf16_hi(a.x) + bf16_hi(b.x), 0.f) * w0.y +
         fmaxf(bf16_lo(a.y) + bf16_lo(b.y), 0.f) * w0.z +
         fmaxf(bf16_hi(a.y) + bf16_hi(b.y), 0.f) * w0.w +
         fmaxf(bf16_lo(a.z) + bf16_lo(b.z), 0.f) * w1.x +
         fmaxf(bf16_hi(a.z) + bf16_hi(b.z), 0.f) * w1.y +
         fmaxf(bf16_lo(a.w) + bf16_lo(b.w), 0.f) * w1.z +
         fmaxf(bf16_hi(a.w) + bf16_hi(b.w), 0.f) * w1.w;
}

__global__ __launch_bounds__(256) void edge_score4(
    const unsigned short* __restrict__ A, const unsigned short* __restrict__ B,
    const int* __restrict__ ps, const int* __restrict__ pd,
    const int* __restrict__ ns, const int* __restrict__ nd,
    const float* __restrict__ Wp2, const float* __restrict__ bp2,
    float* __restrict__ out, int E) {
  const int t = blockIdx.x * blockDim.x + threadIdx.x;
  const int g2 = t >> 4;                // 16 lanes per 4 edges; parity = pos/neg
  const int fl = t & 15;
  const int g = g2 >> 1;
  const int e0 = g * 4;
  if (e0 >= E) return;
  const bool neg = (g2 & 1) != 0;
  const int* ss = neg ? ns : ps;
  const int* dd = neg ? nd : pd;
  float* op = neg ? out + E : out;

  const int4 s4 = *(const int4*)(ss + e0);
  const int4 d4 = *(const int4*)(dd + e0);
  const float4 w0 = *(const float4*)(Wp2 + fl * 8);
  const float4 w1 = *(const float4*)(Wp2 + fl * 8 + 4);
  const size_t fo = (size_t)(fl * 8);

  uint4 a0 = *(const uint4*)(A + (((size_t)s4.x << 7) + fo));
  uint4 b0 = *(const uint4*)(B + (((size_t)d4.x << 7) + fo));
  uint4 a1 = *(const uint4*)(A + (((size_t)s4.y << 7) + fo));
  uint4 b1 = *(const uint4*)(B + (((size_t)d4.y << 7) + fo));
  uint4 a2 = *(const uint4*)(A + (((size_t)s4.z << 7) + fo));
  uint4 b2 = *(const uint4*)(B + (((size_t)d4.z << 7) + fo));
  uint4 a3 = *(const uint4*)(A + (((size_t)s4.w << 7) + fo));
  uint4 b3 = *(const uint4*)(B + (((size_t)d4.w << 7) + fo));

  float p0 = relu_dot8(a0, b0, w0, w1);
  float p1 = relu_dot8(a1, b1, w0, w1);
  float p2 = relu_dot8(a2, b2, w0, w1);
  float p3 = relu_dot8(a3, b3, w0, w1);

  p0 += __shfl_xor(p0, 1); p1 += __shfl_xor(p1, 1); p2 += __shfl_xor(p2, 1); p3 += __shfl_xor(p3, 1);
  p0 += __shfl_xor(p0, 2); p1 += __shfl_xor(p1, 2); p2 += __shfl_xor(p2, 2); p3 += __shfl_xor(p3, 2);
  p0 += __shfl_xor(p0, 4); p1 += __shfl_xor(p1, 4); p2 += __shfl_xor(p2, 4); p3 += __shfl_xor(p3, 4);
  p0 += __shfl_xor(p0, 8); p1 += __shfl_xor(p1, 8); p2 += __shfl_xor(p2, 8); p3 += __shfl_xor(p3, 8);

  if (fl == 0) {
    const float bv = bp2[0];
    *reinterpret_cast<float4*>(op + e0) = make_float4(p0 + bv, p1 + bv, p2 + bv, p3 + bv);
  }
}

// ---------------------------------------------------------------- launcher
extern "C" void kernel_launch(void* const* d_in, const int* in_sizes, int n_in,
                              void* d_out, int out_size, void* d_ws, size_t ws_size,
                              hipStream_t stream) {
  const float* x = (const float*)d_in[0];
  const int* src = (const int*)d_in[1];
  const int* dst = (const int*)d_in[2];
  const int* nsrc = (const int*)d_in[3];
  const int* ndst = (const int*)d_in[4];
  const float* Ws1 = (const float*)d_in[5];
  const float* Wn1 = (const float*)d_in[6];
  const float* b1 = (const float*)d_in[7];
  const float* Ws2 = (const float*)d_in[8];
  const float* Wn2 = (const float*)d_in[9];
  const float* b2 = (const float*)d_in[10];
  const float* Ws3 = (const float*)d_in[11];
  const float* Wn3 = (const float*)d_in[12];
  const float* b3 = (const float*)d_in[13];
  const float* Wp1 = (const float*)d_in[14];
  const float* bp1 = (const float*)d_in[15];
  const float* Wp2 = (const float*)d_in[16];
  const float* bp2 = (const float*)d_in[17];
  float* out = (float*)d_out;

  char* ws = (char*)d_ws;
  size_t off = 0;
  auto alloc = [&](size_t bytes) -> void* {
    void* p = ws + off;
    off += (bytes + 255) & ~(size_t)255;
    return p;
  };
  const size_t NODE_F32 = sizeof(float) * (size_t)N_NODES * D;  // 51.2 MB
  char* region0 = (char*)alloc(NODE_F32);   // bf16 xb | (spare) -> later bf16 Ab | Bb
  char* region1 = (char*)alloc(NODE_F32);   // bf16 hA | hB
  unsigned short* meanb = (unsigned short*)alloc(sizeof(unsigned short) * (size_t)N_NODES * D);
  int* row_start = (int*)alloc(sizeof(int) * (N_NODES + 1));
  int* deg = (int*)alloc(sizeof(int) * N_NODES * 2);  // deg + cursor
  int* cursor = deg + N_NODES;
  int* esrc = (int*)alloc(sizeof(int) * N_EDGES);
  int* partial = (int*)alloc(sizeof(int) * 128);
  unsigned short* wt = (unsigned short*)alloc(sizeof(unsigned short) * 8 * D * D);
  (void)ws_size;

  unsigned short* xb = (unsigned short*)region0;
  unsigned short* hA = (unsigned short*)region1;
  unsigned short* hB = hA + (size_t)N_NODES * D;
  unsigned short* Ab = xb;                              // xb dead after layer-1 MLP
  unsigned short* Bb = xb + (size_t)N_NODES * D;        // second half of region0

  // ---- conversions
  f32_to_bf16_vec<<<(N_NODES * D / 4 + 255) / 256, 256, 0, stream>>>(x, xb, N_NODES * D / 4);
  transpose_w<<<512, 256, 0, stream>>>(Ws1, Wn1, Ws2, Wn2, Ws3, Wn3, Wp1, Wp1 + D * D, wt);

  // ---- CSR build (pos edges; reused by all 3 layers)
  zero_i32<<<(2 * N_NODES + 255) / 256, 256, 0, stream>>>(deg, 2 * N_NODES);
  hist_kernel<<<(N_EDGES + 255) / 256, 256, 0, stream>>>(dst, deg, N_EDGES);
  scan_blocksum<<<SCAN_BLOCKS, 256, 0, stream>>>(deg, partial, N_NODES);
  scan_offsets<<<1, 128, 0, stream>>>(partial, row_start, SCAN_BLOCKS, N_NODES);
  scan_final<<<SCAN_BLOCKS, 256, 0, stream>>>(deg, partial, row_start, N_NODES);
  fill_kernel<<<(N_EDGES + 255) / 256, 256, 0, stream>>>(src, dst, row_start, cursor, esrc, N_EDGES);

  const int gatherBlocks = (N_NODES * 16 + 255) / 256;  // 6250
  const int CHUNKS = (N_NODES + 15) / 16;               // 6250 16-row chunks
  const int predBlocks = (N_NODES + 127) / 128;         // 782 (2 tiles/block)
  const int edgeBlocks = (2 * (N_EDGES / 4) * 16) / 256;  // 20000 (pos+neg fused)

  // ---- layer 1 (persistent weights)
  gather_mean<<<gatherBlocks, 256, 0, stream>>>(xb, row_start, esrc, meanb, N_NODES);
  layer_persist<<<256, 512, 0, stream>>>(
      xb, meanb, wt, wt + 16384, b1, hA, N_NODES, CHUNKS);
  // ---- layer 2 (persistent weights)
  gather_mean<<<gatherBlocks, 256, 0, stream>>>(hA, row_start, esrc, meanb, N_NODES);
  layer_persist<<<256, 512, 0, stream>>>(
      hA, meanb, wt + 2 * 16384, wt + 3 * 16384, b2, hB, N_NODES, CHUNKS);
  // ---- layer 3 + predictor
  gather_mean<<<gatherBlocks, 256, 0, stream>>>(hB, row_start, esrc, meanb, N_NODES);
  layer_mlp<true><<<predBlocks, 256, 0, stream>>>(
      hB, meanb, wt + 4 * 16384, wt + 5 * 16384, b3, wt + 6 * 16384, wt + 7 * 16384, bp1,
      Ab, Bb, N_NODES);
  // ---- edge scores: pos+neg in one dispatch (disjoint outputs)
  edge_score4<<<edgeBlocks, 256, 0, stream>>>(Ab, Bb, src, dst, nsrc, ndst, Wp2, bp2, out, N_EDGES);
}

// Round 10
// 450.015 us; speedup vs baseline: 1.1535x; 1.1535x over previous
//
#include <hip/hip_runtime.h>

#define N_NODES 100000
#define N_EDGES 640000
#define D 128
#define SCAN_TILE 1024
#define SCAN_BLOCKS ((N_NODES + SCAN_TILE - 1) / SCAN_TILE)  // 98

typedef __attribute__((ext_vector_type(8))) short bf16x8;   // 8 bf16 = 4 VGPRs
typedef __attribute__((ext_vector_type(4))) float f32x4;

__device__ __forceinline__ unsigned short f32_to_bf16(float f) {
  union { float f; unsigned int u; } v; v.f = f;
  unsigned int u = v.u;
  unsigned int r = (u + 0x7fffu + ((u >> 16) & 1u)) >> 16;  // RNE
  return (unsigned short)r;
}
__device__ __forceinline__ float bf16_lo(unsigned int u) { return __uint_as_float(u << 16); }
__device__ __forceinline__ float bf16_hi(unsigned int u) { return __uint_as_float(u & 0xffff0000u); }

__device__ __forceinline__ void acc8(float* a, uint4 r) {
  a[0] += bf16_lo(r.x); a[1] += bf16_hi(r.x);
  a[2] += bf16_lo(r.y); a[3] += bf16_hi(r.y);
  a[4] += bf16_lo(r.z); a[5] += bf16_hi(r.z);
  a[6] += bf16_lo(r.w); a[7] += bf16_hi(r.w);
}

// ---------------------------------------------------------------- utilities
__global__ void zero_i32(int* __restrict__ p, int n) {
  int i = blockIdx.x * blockDim.x + threadIdx.x;
  if (i < n) p[i] = 0;
}

__global__ void f32_to_bf16_vec(const float* __restrict__ in, unsigned short* __restrict__ out, int n4) {
  int i = blockIdx.x * blockDim.x + threadIdx.x;
  if (i < n4) {
    float4 v = ((const float4*)in)[i];
    ushort4 o;
    o.x = f32_to_bf16(v.x); o.y = f32_to_bf16(v.y);
    o.z = f32_to_bf16(v.z); o.w = f32_to_bf16(v.w);
    ((ushort4*)out)[i] = o;
  }
}

// 8 weight matrices [128x128] fp32 row-major [k][n] -> bf16 transposed Wt[n][k]
__global__ void transpose_w(const float* __restrict__ W0, const float* __restrict__ W1,
                            const float* __restrict__ W2, const float* __restrict__ W3,
                            const float* __restrict__ W4, const float* __restrict__ W5,
                            const float* __restrict__ W6, const float* __restrict__ W7,
                            unsigned short* __restrict__ wt) {
  int id = blockIdx.x * 256 + threadIdx.x;  // 512 blocks x 256 = 131072
  int mat = id >> 14;
  int rem = id & 16383;
  int n = rem >> 7, k = rem & 127;
  const float* Wm = mat < 4 ? (mat < 2 ? (mat == 0 ? W0 : W1) : (mat == 2 ? W2 : W3))
                            : (mat < 6 ? (mat == 4 ? W4 : W5) : (mat == 6 ? W6 : W7));
  wt[id] = f32_to_bf16(Wm[k * D + n]);
}

// ------------------------------------------------------------- CSR building (pos edges only)
__global__ void hist_kernel(const int* __restrict__ dst, int* __restrict__ deg, int E) {
  int i = blockIdx.x * blockDim.x + threadIdx.x;
  if (i < E) atomicAdd(&deg[dst[i]], 1);
}

__global__ void scan_blocksum(const int* __restrict__ deg, int* __restrict__ partial, int n) {
  __shared__ int lds[256];
  const int tid = threadIdx.x;
  const int base = blockIdx.x * SCAN_TILE + tid * 4;
  int s = 0;
#pragma unroll
  for (int j = 0; j < 4; ++j) {
    int i = base + j;
    if (i < n) s += deg[i];
  }
  lds[tid] = s;
  __syncthreads();
  for (int off = 128; off > 0; off >>= 1) {
    if (tid < off) lds[tid] += lds[tid + off];
    __syncthreads();
  }
  if (tid == 0) partial[blockIdx.x] = lds[0];
}

__global__ void scan_offsets(int* __restrict__ partial, int* __restrict__ row_start, int nb, int n) {
  __shared__ int lds[128];
  const int tid = threadIdx.x;
  int v = (tid < nb) ? partial[tid] : 0;
  lds[tid] = v;
  __syncthreads();
  for (int off = 1; off < 128; off <<= 1) {
    int t = (tid >= off) ? lds[tid - off] : 0;
    __syncthreads();
    lds[tid] += t;
    __syncthreads();
  }
  if (tid < nb) partial[tid] = (tid == 0) ? 0 : lds[tid - 1];
  if (tid == 0) row_start[n] = lds[nb - 1];
}

__global__ void scan_final(const int* __restrict__ deg, const int* __restrict__ partial,
                           int* __restrict__ row_start, int n) {
  __shared__ int lds[256];
  const int tid = threadIdx.x;
  const int base = blockIdx.x * SCAN_TILE + tid * 4;
  int d[4];
  int s = 0;
#pragma unroll
  for (int j = 0; j < 4; ++j) {
    int i = base + j;
    d[j] = (i < n) ? deg[i] : 0;
    s += d[j];
  }
  lds[tid] = s;
  __syncthreads();
  for (int off = 1; off < 256; off <<= 1) {
    int t = (tid >= off) ? lds[tid - off] : 0;
    __syncthreads();
    lds[tid] += t;
    __syncthreads();
  }
  int pre = partial[blockIdx.x] + lds[tid] - s;
#pragma unroll
  for (int j = 0; j < 4; ++j) {
    int i = base + j;
    if (i < n) {
      row_start[i] = pre;
      pre += d[j];
    }
  }
}

__global__ void fill_kernel(const int* __restrict__ src, const int* __restrict__ dst,
                            const int* __restrict__ row_start, int* __restrict__ cursor,
                            int* __restrict__ esrc, int E) {
  int i = blockIdx.x * blockDim.x + threadIdx.x;
  if (i < E) {
    int d = dst[i];
    int pos = atomicAdd(&cursor[d], 1);
    esrc[row_start[d] + pos] = src[i];
  }
}

// ----------------------------------------------------- gather-only mean kernel
// One node per 16-lane group, 16 nodes per 256-thread block -> 6250 blocks.
// No LDS, no MFMA, low VGPR: occupancy-driven TLP is the latency hiding.
// Measured at the ~3.6 TB/s random-gather ceiling (L2-hit ~50%, structural
// for a random graph: any 2MB x 2MB L2 tile contains <1 reuse per row).
__global__ __launch_bounds__(256) void gather_mean(
    const unsigned short* __restrict__ hin,
    const int* __restrict__ row_start, const int* __restrict__ esrc,
    unsigned short* __restrict__ mean, int M) {
  const int t = blockIdx.x * blockDim.x + threadIdx.x;
  const int node = t >> 4;
  const int fl = t & 15;  // 16 B of the row per lane
  if (node >= M) return;
  const int s0 = row_start[node], s1 = row_start[node + 1];
  float ac[8] = {0.f, 0.f, 0.f, 0.f, 0.f, 0.f, 0.f, 0.f};
  int e = s0;
  for (; e + 4 <= s1; e += 4) {
    int i0 = esrc[e], i1 = esrc[e + 1], i2 = esrc[e + 2], i3 = esrc[e + 3];
    uint4 r0 = *(const uint4*)(hin + (((size_t)i0) << 7) + fl * 8);
    uint4 r1 = *(const uint4*)(hin + (((size_t)i1) << 7) + fl * 8);
    uint4 r2 = *(const uint4*)(hin + (((size_t)i2) << 7) + fl * 8);
    uint4 r3 = *(const uint4*)(hin + (((size_t)i3) << 7) + fl * 8);
    acc8(ac, r0); acc8(ac, r1); acc8(ac, r2); acc8(ac, r3);
  }
  for (; e < s1; ++e) {
    uint4 r0 = *(const uint4*)(hin + (((size_t)esrc[e]) << 7) + fl * 8);
    acc8(ac, r0);
  }
  const float inv = 1.0f / (float)max(s1 - s0, 1);
#pragma unroll
  for (int k = 0; k < 8; ++k) ac[k] *= inv;
  uint4 o;
  o.x = (unsigned)f32_to_bf16(ac[0]) | ((unsigned)f32_to_bf16(ac[1]) << 16);
  o.y = (unsigned)f32_to_bf16(ac[2]) | ((unsigned)f32_to_bf16(ac[3]) << 16);
  o.z = (unsigned)f32_to_bf16(ac[4]) | ((unsigned)f32_to_bf16(ac[5]) << 16);
  o.w = (unsigned)f32_to_bf16(ac[6]) | ((unsigned)f32_to_bf16(ac[7]) << 16);
  *reinterpret_cast<uint4*>(mean + (((size_t)node) << 7) + fl * 8) = o;
}

// ----------------------------------------------------- dense MLP kernel (r7: best-measured layers)
// Block = 64 nodes, 4 waves, wave w owns output rows 16w..16w+15.
// out = hin@Ws + mean@Wn + b via MFMA; single-buffered weight panels in LDS,
// 2-barrier phase structure. SESSION RECORD: five structural variants
// (r5 single-buf, r6 double-buf, r7 min-LDS, r8 2-tile, r9 persistent-weight)
// all landed 40-48us or worse -- this latency plateau is robust to per-block
// resources, tile shape, and staging strategy. r9's 104KB-LDS persistent
// kernel serialized the grid entirely (occupancy 0.13%!). Keeping r7.
//   non-PRED: epilogue reuses wl (weights dead; prebar drains readers),
//   LDS 17.7 KB. PRED: separate mt for h3 (survives restaging), 34.8 KB.
// EPILOGUE: coalesced via LDS transpose (scattered 2B stores = 2x write amp).
template <bool PRED>
__global__ __launch_bounds__(256) void layer_mlp(
    const unsigned short* __restrict__ hin,
    const unsigned short* __restrict__ mean,
    const unsigned short* __restrict__ Wts, const unsigned short* __restrict__ Wtn,
    const float* __restrict__ bias,
    const unsigned short* __restrict__ WtA, const unsigned short* __restrict__ WtB,
    const float* __restrict__ biasA,
    unsigned short* __restrict__ out0, unsigned short* __restrict__ out1, int M) {
  __shared__ unsigned short wl[64][136];             // 17.4 KB weight panel
  __shared__ unsigned short mt[PRED ? 64 : 1][136];  // h3/epilogue tile (PRED only)
  const int tid = threadIdx.x;
  const int lane = tid & 63;
  const int wave = tid >> 6;
  const int m0 = blockIdx.x * 64;
  const int row = lane & 15;
  const int q = lane >> 4;
  const int mw = m0 + wave * 16;
  const int mload = min(mw + row, M - 1);
  const int lrow = wave * 16 + row;  // local row 0..63

  // epilogue transpose tile: PRED -> mt, non-PRED -> wl (weights dead by epilogue)
  unsigned short (*et)[136];
  if constexpr (PRED) et = mt; else et = wl;

  auto stage64 = [&](const unsigned short* W, int half) {
#pragma unroll
    for (int i = 0; i < 4; ++i) {
      int seg = i * 256 + tid;
      int r = seg >> 4, o = (seg & 15) * 8;
      *reinterpret_cast<bf16x8*>(&wl[r][o]) =
          *reinterpret_cast<const bf16x8*>(W + (size_t)(half * 64 + r) * D + o);
    }
  };
  auto mfma_half = [&](bf16x8* a, f32x4* accp) {
#pragma unroll
    for (int s = 0; s < 4; ++s)
#pragma unroll
      for (int t = 0; t < 4; ++t) {
        bf16x8 b = *reinterpret_cast<const bf16x8*>(&wl[t * 16 + row][s * 32 + q * 8]);
        accp[t] = __builtin_amdgcn_mfma_f32_16x16x32_bf16(a[s], b, accp[t], 0, 0, 0);
      }
  };
  // coalesced epilogue: acc (+bias) -> et -> barrier -> contiguous uint4 stores.
  // prebar: barrier BEFORE the et writes (needed when et aliases wl and other
  // waves may still be reading wl in their last mfma_half).
  auto epilogue = [&](f32x4* accp, const float* bvec, unsigned short* dst, bool prebar) {
    if (prebar) __syncthreads();
#pragma unroll
    for (int t = 0; t < 8; ++t) {
      const int col = t * 16 + row;
      const float bv = bvec ? bvec[col] : 0.f;
#pragma unroll
      for (int r = 0; r < 4; ++r)
        et[wave * 16 + q * 4 + r][col] = f32_to_bf16(accp[t][r] + bv);
    }
    __syncthreads();
#pragma unroll
    for (int i = 0; i < 4; ++i) {
      int idx = i * 256 + tid;
      int r2 = idx >> 4;
      int c8 = (idx & 15) * 8;
      int m = m0 + r2;
      if (m < M)
        *reinterpret_cast<uint4*>(dst + (size_t)m * D + c8) =
            *reinterpret_cast<const uint4*>(&et[r2][c8]);
    }
  };

  // ---- stage Ws half 0; A fragments stream in under the staging ----
  stage64(Wts, 0);
  bf16x8 ah[4], am[4];
#pragma unroll
  for (int s = 0; s < 4; ++s) {
    ah[s] = *reinterpret_cast<const bf16x8*>(hin + (size_t)mload * D + s * 32 + q * 8);
    am[s] = *reinterpret_cast<const bf16x8*>(mean + (size_t)mload * D + s * 32 + q * 8);
  }
  __syncthreads();

  f32x4 acc[8];
#pragma unroll
  for (int t = 0; t < 8; ++t) acc[t] = (f32x4){0.f, 0.f, 0.f, 0.f};

  mfma_half(ah, acc);                 // hin @ Ws, n 0..63
  __syncthreads(); stage64(Wts, 1); __syncthreads();
  mfma_half(ah, acc + 4);             // hin @ Ws, n 64..127
  __syncthreads(); stage64(Wtn, 0); __syncthreads();
  mfma_half(am, acc);                 // mean @ Wn, n 0..63
  __syncthreads(); stage64(Wtn, 1); __syncthreads();
  mfma_half(am, acc + 4);             // mean @ Wn, n 64..127

  if (!PRED) {
    epilogue(acc, bias, out0, /*prebar=*/true);  // et = wl: wait for all waves' mfma
    return;
  }

  // ================= PRED tail (layer 3) =================
  __syncthreads();  // all waves done with wl(Wtn half1) before restage
  // ---- h3 (bf16, bias applied) into mt own rows; stage WtA half 0 ----
#pragma unroll
  for (int t = 0; t < 8; ++t) {
    const int col = t * 16 + row;
    const float bv = bias[col];
#pragma unroll
    for (int r = 0; r < 4; ++r)
      mt[wave * 16 + q * 4 + r][col] = f32_to_bf16(acc[t][r] + bv);
  }
  stage64(WtA, 0);
  __syncthreads();
  // ---- h3 A-fragments (each wave reads only rows it wrote) ----
  bf16x8 ap[4];
#pragma unroll
  for (int s = 0; s < 4; ++s)
    ap[s] = *reinterpret_cast<const bf16x8*>(&mt[lrow][s * 32 + q * 8]);

#pragma unroll
  for (int t = 0; t < 8; ++t) acc[t] = (f32x4){0.f, 0.f, 0.f, 0.f};
  mfma_half(ap, acc);                 // h3 @ WtA, n 0..63
  __syncthreads(); stage64(WtA, 1); __syncthreads();
  mfma_half(ap, acc + 4);             // h3 @ WtA, n 64..127
  epilogue(acc, biasA, out0, /*prebar=*/false);  // et = mt, own-row writes safe
  __syncthreads(); stage64(WtB, 0); __syncthreads();
#pragma unroll
  for (int t = 0; t < 8; ++t) acc[t] = (f32x4){0.f, 0.f, 0.f, 0.f};
  mfma_half(ap, acc);                 // h3 @ WtB, n 0..63
  __syncthreads(); stage64(WtB, 1); __syncthreads();
  mfma_half(ap, acc + 4);             // h3 @ WtB, n 64..127
  epilogue(acc, nullptr, out1, /*prebar=*/false);  // epilogue-A reads drained 2 barriers ago
}

// ----------------------------------------------------- edge MLP score, fused pos+neg
// score = relu(A[s]+B[d]).Wp2 + bp2 (bp1 folded into A). One dispatch for both
// edge sets (parity-interleaved groups): measured r9 fused 85.4us vs r8 split
// 93us -- the inter-dispatch drain/ramp outweighed the width gain. 4 edges /
// 16-lane group, 8 row-gathers in flight, int4 index loads, one coalesced
// float4 store per group. At the ~3.6 TB/s random-gather ceiling.
__device__ __forceinline__ float relu_dot8(uint4 a, uint4 b, float4 w0, float4 w1) {
  return fmaxf(bf16_lo(a.x) + bf16_lo(b.x), 0.f) * w0.x +
         fmaxf(bf16_hi(a.x) + bf16_hi(b.x), 0.f) * w0.y +
         fmaxf(bf16_lo(a.y) + bf16_lo(b.y), 0.f) * w0.z +
         fmaxf(bf16_hi(a.y) + bf16_hi(b.y), 0.f) * w0.w +
         fmaxf(bf16_lo(a.z) + bf16_lo(b.z), 0.f) * w1.x +
         fmaxf(bf16_hi(a.z) + bf16_hi(b.z), 0.f) * w1.y +
         fmaxf(bf16_lo(a.w) + bf16_lo(b.w), 0.f) * w1.z +
         fmaxf(bf16_hi(a.w) + bf16_hi(b.w), 0.f) * w1.w;
}

__global__ __launch_bounds__(256) void edge_score4(
    const unsigned short* __restrict__ A, const unsigned short* __restrict__ B,
    const int* __restrict__ ps, const int* __restrict__ pd,
    const int* __restrict__ ns, const int* __restrict__ nd,
    const float* __restrict__ Wp2, const float* __restrict__ bp2,
    float* __restrict__ out, int E) {
  const int t = blockIdx.x * blockDim.x + threadIdx.x;
  const int g2 = t >> 4;                // 16 lanes per 4 edges; parity = pos/neg
  const int fl = t & 15;
  const int g = g2 >> 1;
  const int e0 = g * 4;
  if (e0 >= E) return;
  const bool neg = (g2 & 1) != 0;
  const int* ss = neg ? ns : ps;
  const int* dd = neg ? nd : pd;
  float* op = neg ? out + E : out;

  const int4 s4 = *(const int4*)(ss + e0);
  const int4 d4 = *(const int4*)(dd + e0);
  const float4 w0 = *(const float4*)(Wp2 + fl * 8);
  const float4 w1 = *(const float4*)(Wp2 + fl * 8 + 4);
  const size_t fo = (size_t)(fl * 8);

  uint4 a0 = *(const uint4*)(A + (((size_t)s4.x << 7) + fo));
  uint4 b0 = *(const uint4*)(B + (((size_t)d4.x << 7) + fo));
  uint4 a1 = *(const uint4*)(A + (((size_t)s4.y << 7) + fo));
  uint4 b1 = *(const uint4*)(B + (((size_t)d4.y << 7) + fo));
  uint4 a2 = *(const uint4*)(A + (((size_t)s4.z << 7) + fo));
  uint4 b2 = *(const uint4*)(B + (((size_t)d4.z << 7) + fo));
  uint4 a3 = *(const uint4*)(A + (((size_t)s4.w << 7) + fo));
  uint4 b3 = *(const uint4*)(B + (((size_t)d4.w << 7) + fo));

  float p0 = relu_dot8(a0, b0, w0, w1);
  float p1 = relu_dot8(a1, b1, w0, w1);
  float p2 = relu_dot8(a2, b2, w0, w1);
  float p3 = relu_dot8(a3, b3, w0, w1);

  p0 += __shfl_xor(p0, 1); p1 += __shfl_xor(p1, 1); p2 += __shfl_xor(p2, 1); p3 += __shfl_xor(p3, 1);
  p0 += __shfl_xor(p0, 2); p1 += __shfl_xor(p1, 2); p2 += __shfl_xor(p2, 2); p3 += __shfl_xor(p3, 2);
  p0 += __shfl_xor(p0, 4); p1 += __shfl_xor(p1, 4); p2 += __shfl_xor(p2, 4); p3 += __shfl_xor(p3, 4);
  p0 += __shfl_xor(p0, 8); p1 += __shfl_xor(p1, 8); p2 += __shfl_xor(p2, 8); p3 += __shfl_xor(p3, 8);

  if (fl == 0) {
    const float bv = bp2[0];
    *reinterpret_cast<float4*>(op + e0) = make_float4(p0 + bv, p1 + bv, p2 + bv, p3 + bv);
  }
}

// ---------------------------------------------------------------- launcher
extern "C" void kernel_launch(void* const* d_in, const int* in_sizes, int n_in,
                              void* d_out, int out_size, void* d_ws, size_t ws_size,
                              hipStream_t stream) {
  const float* x = (const float*)d_in[0];
  const int* src = (const int*)d_in[1];
  const int* dst = (const int*)d_in[2];
  const int* nsrc = (const int*)d_in[3];
  const int* ndst = (const int*)d_in[4];
  const float* Ws1 = (const float*)d_in[5];
  const float* Wn1 = (const float*)d_in[6];
  const float* b1 = (const float*)d_in[7];
  const float* Ws2 = (const float*)d_in[8];
  const float* Wn2 = (const float*)d_in[9];
  const float* b2 = (const float*)d_in[10];
  const float* Ws3 = (const float*)d_in[11];
  const float* Wn3 = (const float*)d_in[12];
  const float* b3 = (const float*)d_in[13];
  const float* Wp1 = (const float*)d_in[14];
  const float* bp1 = (const float*)d_in[15];
  const float* Wp2 = (const float*)d_in[16];
  const float* bp2 = (const float*)d_in[17];
  float* out = (float*)d_out;

  char* ws = (char*)d_ws;
  size_t off = 0;
  auto alloc = [&](size_t bytes) -> void* {
    void* p = ws + off;
    off += (bytes + 255) & ~(size_t)255;
    return p;
  };
  const size_t NODE_F32 = sizeof(float) * (size_t)N_NODES * D;  // 51.2 MB
  char* region0 = (char*)alloc(NODE_F32);   // bf16 xb | (spare) -> later bf16 Ab | Bb
  char* region1 = (char*)alloc(NODE_F32);   // bf16 hA | hB
  unsigned short* meanb = (unsigned short*)alloc(sizeof(unsigned short) * (size_t)N_NODES * D);
  int* row_start = (int*)alloc(sizeof(int) * (N_NODES + 1));
  int* deg = (int*)alloc(sizeof(int) * N_NODES * 2);  // deg + cursor
  int* cursor = deg + N_NODES;
  int* esrc = (int*)alloc(sizeof(int) * N_EDGES);
  int* partial = (int*)alloc(sizeof(int) * 128);
  unsigned short* wt = (unsigned short*)alloc(sizeof(unsigned short) * 8 * D * D);
  (void)ws_size;

  unsigned short* xb = (unsigned short*)region0;
  unsigned short* hA = (unsigned short*)region1;
  unsigned short* hB = hA + (size_t)N_NODES * D;
  unsigned short* Ab = xb;                              // xb dead after layer-1 MLP
  unsigned short* Bb = xb + (size_t)N_NODES * D;        // second half of region0

  // ---- conversions
  f32_to_bf16_vec<<<(N_NODES * D / 4 + 255) / 256, 256, 0, stream>>>(x, xb, N_NODES * D / 4);
  transpose_w<<<512, 256, 0, stream>>>(Ws1, Wn1, Ws2, Wn2, Ws3, Wn3, Wp1, Wp1 + D * D, wt);

  // ---- CSR build (pos edges; reused by all 3 layers)
  zero_i32<<<(2 * N_NODES + 255) / 256, 256, 0, stream>>>(deg, 2 * N_NODES);
  hist_kernel<<<(N_EDGES + 255) / 256, 256, 0, stream>>>(dst, deg, N_EDGES);
  scan_blocksum<<<SCAN_BLOCKS, 256, 0, stream>>>(deg, partial, N_NODES);
  scan_offsets<<<1, 128, 0, stream>>>(partial, row_start, SCAN_BLOCKS, N_NODES);
  scan_final<<<SCAN_BLOCKS, 256, 0, stream>>>(deg, partial, row_start, N_NODES);
  fill_kernel<<<(N_EDGES + 255) / 256, 256, 0, stream>>>(src, dst, row_start, cursor, esrc, N_EDGES);

  const int gatherBlocks = (N_NODES * 16 + 255) / 256;    // 6250
  const int mlpBlocks = (N_NODES + 63) / 64;              // 1563
  const int edgeBlocks = (2 * (N_EDGES / 4) * 16) / 256;  // 20000 (pos+neg fused)

  // ---- layer 1
  gather_mean<<<gatherBlocks, 256, 0, stream>>>(xb, row_start, esrc, meanb, N_NODES);
  layer_mlp<false><<<mlpBlocks, 256, 0, stream>>>(
      xb, meanb, wt, wt + 16384, b1, nullptr, nullptr, nullptr, hA, nullptr, N_NODES);
  // ---- layer 2
  gather_mean<<<gatherBlocks, 256, 0, stream>>>(hA, row_start, esrc, meanb, N_NODES);
  layer_mlp<false><<<mlpBlocks, 256, 0, stream>>>(
      hA, meanb, wt + 2 * 16384, wt + 3 * 16384, b2, nullptr, nullptr, nullptr, hB, nullptr, N_NODES);
  // ---- layer 3 + predictor
  gather_mean<<<gatherBlocks, 256, 0, stream>>>(hB, row_start, esrc, meanb, N_NODES);
  layer_mlp<true><<<mlpBlocks, 256, 0, stream>>>(
      hB, meanb, wt + 4 * 16384, wt + 5 * 16384, b3, wt + 6 * 16384, wt + 7 * 16384, bp1,
      Ab, Bb, N_NODES);
  // ---- edge scores: pos+neg in one dispatch (disjoint outputs)
  edge_score4<<<edgeBlocks, 256, 0, stream>>>(Ab, Bb, src, dst, nsrc, ndst, Wp2, bp2, out, N_EDGES);
}

// Round 11
// 447.325 us; speedup vs baseline: 1.1605x; 1.0060x over previous
//
#include <hip/hip_runtime.h>

#define N_NODES 100000
#define N_EDGES 640000
#define D 128
#define SCAN_TILE 1024
#define SCAN_BLOCKS ((N_NODES + SCAN_TILE - 1) / SCAN_TILE)  // 98

typedef __attribute__((ext_vector_type(8))) short bf16x8;   // 8 bf16 = 4 VGPRs
typedef __attribute__((ext_vector_type(4))) float f32x4;

__device__ __forceinline__ unsigned short f32_to_bf16(float f) {
  union { float f; unsigned int u; } v; v.f = f;
  unsigned int u = v.u;
  unsigned int r = (u + 0x7fffu + ((u >> 16) & 1u)) >> 16;  // RNE
  return (unsigned short)r;
}
__device__ __forceinline__ float bf16_lo(unsigned int u) { return __uint_as_float(u << 16); }
__device__ __forceinline__ float bf16_hi(unsigned int u) { return __uint_as_float(u & 0xffff0000u); }

__device__ __forceinline__ void acc8(float* a, uint4 r) {
  a[0] += bf16_lo(r.x); a[1] += bf16_hi(r.x);
  a[2] += bf16_lo(r.y); a[3] += bf16_hi(r.y);
  a[4] += bf16_lo(r.z); a[5] += bf16_hi(r.z);
  a[6] += bf16_lo(r.w); a[7] += bf16_hi(r.w);
}

// ---------------------------------------------------------------- utilities
__global__ void zero_i32(int* __restrict__ p, int n) {
  int i = blockIdx.x * blockDim.x + threadIdx.x;
  if (i < n) p[i] = 0;
}

__global__ void f32_to_bf16_vec(const float* __restrict__ in, unsigned short* __restrict__ out, int n4) {
  int i = blockIdx.x * blockDim.x + threadIdx.x;
  if (i < n4) {
    float4 v = ((const float4*)in)[i];
    ushort4 o;
    o.x = f32_to_bf16(v.x); o.y = f32_to_bf16(v.y);
    o.z = f32_to_bf16(v.z); o.w = f32_to_bf16(v.w);
    ((ushort4*)out)[i] = o;
  }
}

// 8 weight matrices [128x128] fp32 row-major [k][n] -> bf16 transposed Wt[n][k]
__global__ void transpose_w(const float* __restrict__ W0, const float* __restrict__ W1,
                            const float* __restrict__ W2, const float* __restrict__ W3,
                            const float* __restrict__ W4, const float* __restrict__ W5,
                            const float* __restrict__ W6, const float* __restrict__ W7,
                            unsigned short* __restrict__ wt) {
  int id = blockIdx.x * 256 + threadIdx.x;  // 512 blocks x 256 = 131072
  int mat = id >> 14;
  int rem = id & 16383;
  int n = rem >> 7, k = rem & 127;
  const float* Wm = mat < 4 ? (mat < 2 ? (mat == 0 ? W0 : W1) : (mat == 2 ? W2 : W3))
                            : (mat < 6 ? (mat == 4 ? W4 : W5) : (mat == 6 ? W6 : W7));
  wt[id] = f32_to_bf16(Wm[k * D + n]);
}

// ------------------------------------------------------------- CSR building (pos edges only)
__global__ void hist_kernel(const int* __restrict__ dst, int* __restrict__ deg, int E) {
  int i = blockIdx.x * blockDim.x + threadIdx.x;
  if (i < E) atomicAdd(&deg[dst[i]], 1);
}

__global__ void scan_blocksum(const int* __restrict__ deg, int* __restrict__ partial, int n) {
  __shared__ int lds[256];
  const int tid = threadIdx.x;
  const int base = blockIdx.x * SCAN_TILE + tid * 4;
  int s = 0;
#pragma unroll
  for (int j = 0; j < 4; ++j) {
    int i = base + j;
    if (i < n) s += deg[i];
  }
  lds[tid] = s;
  __syncthreads();
  for (int off = 128; off > 0; off >>= 1) {
    if (tid < off) lds[tid] += lds[tid + off];
    __syncthreads();
  }
  if (tid == 0) partial[blockIdx.x] = lds[0];
}

__global__ void scan_offsets(int* __restrict__ partial, int* __restrict__ row_start, int nb, int n) {
  __shared__ int lds[128];
  const int tid = threadIdx.x;
  int v = (tid < nb) ? partial[tid] : 0;
  lds[tid] = v;
  __syncthreads();
  for (int off = 1; off < 128; off <<= 1) {
    int t = (tid >= off) ? lds[tid - off] : 0;
    __syncthreads();
    lds[tid] += t;
    __syncthreads();
  }
  if (tid < nb) partial[tid] = (tid == 0) ? 0 : lds[tid - 1];
  if (tid == 0) row_start[n] = lds[nb - 1];
}

__global__ void scan_final(const int* __restrict__ deg, const int* __restrict__ partial,
                           int* __restrict__ row_start, int n) {
  __shared__ int lds[256];
  const int tid = threadIdx.x;
  const int base = blockIdx.x * SCAN_TILE + tid * 4;
  int d[4];
  int s = 0;
#pragma unroll
  for (int j = 0; j < 4; ++j) {
    int i = base + j;
    d[j] = (i < n) ? deg[i] : 0;
    s += d[j];
  }
  lds[tid] = s;
  __syncthreads();
  for (int off = 1; off < 256; off <<= 1) {
    int t = (tid >= off) ? lds[tid - off] : 0;
    __syncthreads();
    lds[tid] += t;
    __syncthreads();
  }
  int pre = partial[blockIdx.x] + lds[tid] - s;
#pragma unroll
  for (int j = 0; j < 4; ++j) {
    int i = base + j;
    if (i < n) {
      row_start[i] = pre;
      pre += d[j];
    }
  }
}

__global__ void fill_kernel(const int* __restrict__ src, const int* __restrict__ dst,
                            const int* __restrict__ row_start, int* __restrict__ cursor,
                            int* __restrict__ esrc, int E) {
  int i = blockIdx.x * blockDim.x + threadIdx.x;
  if (i < E) {
    int d = dst[i];
    int pos = atomicAdd(&cursor[d], 1);
    esrc[row_start[d] + pos] = src[i];
  }
}

// ----------------------------------------------------- gather-only mean kernel, 8-deep batches
// One node per 16-lane group, 16 nodes per 256-thread block -> 6250 blocks.
// ROUND-10 FINDING: edge_score4 (8 independent row-gathers in flight) runs at
// ~7.6 TB/s effective vs gather_mean's ~5 TB/s (4 in flight + 1-3 SERIAL
// single-row tail rounds for the mean-degree-6.4 nodes). Fix: one masked
// 8-batch per ceil(deg/8) -- indices clamped to min(e+j, s1-1) (pad lanes
// duplicate the last index = same cache line, ~free), all 8 row gathers
// issued concurrently, accumulation predicated on e+j < s1. For ~80% of
// nodes the whole gather is ONE index round + ONE row round.
__global__ __launch_bounds__(256) void gather_mean(
    const unsigned short* __restrict__ hin,
    const int* __restrict__ row_start, const int* __restrict__ esrc,
    unsigned short* __restrict__ mean, int M) {
  const int t = blockIdx.x * blockDim.x + threadIdx.x;
  const int node = t >> 4;
  const int fl = t & 15;  // 16 B of the row per lane
  if (node >= M) return;
  const int s0 = row_start[node], s1 = row_start[node + 1];
  float ac[8] = {0.f, 0.f, 0.f, 0.f, 0.f, 0.f, 0.f, 0.f};
  for (int e = s0; e < s1; e += 8) {
    int idx[8];
#pragma unroll
    for (int j = 0; j < 8; ++j) idx[j] = esrc[min(e + j, s1 - 1)];
    uint4 r[8];
#pragma unroll
    for (int j = 0; j < 8; ++j)
      r[j] = *(const uint4*)(hin + (((size_t)idx[j]) << 7) + fl * 8);
#pragma unroll
    for (int j = 0; j < 8; ++j)
      if (e + j < s1) acc8(ac, r[j]);
  }
  const float inv = 1.0f / (float)max(s1 - s0, 1);
#pragma unroll
  for (int k = 0; k < 8; ++k) ac[k] *= inv;
  uint4 o;
  o.x = (unsigned)f32_to_bf16(ac[0]) | ((unsigned)f32_to_bf16(ac[1]) << 16);
  o.y = (unsigned)f32_to_bf16(ac[2]) | ((unsigned)f32_to_bf16(ac[3]) << 16);
  o.z = (unsigned)f32_to_bf16(ac[4]) | ((unsigned)f32_to_bf16(ac[5]) << 16);
  o.w = (unsigned)f32_to_bf16(ac[6]) | ((unsigned)f32_to_bf16(ac[7]) << 16);
  *reinterpret_cast<uint4*>(mean + (((size_t)node) << 7) + fl * 8) = o;
}

// ----------------------------------------------------- dense MLP kernel (r7: best-measured layers)
// Block = 64 nodes, 4 waves, wave w owns output rows 16w..16w+15.
// out = hin@Ws + mean@Wn + b via MFMA; single-buffered weight panels in LDS,
// 2-barrier phase structure. SESSION RECORD: five structural variants
// (r5 single-buf, r6 double-buf, r7 min-LDS, r8 2-tile, r9 persistent-weight)
// all landed 40-48us or worse -- this latency plateau is robust to per-block
// resources, tile shape, and staging strategy. Keeping r7.
//   non-PRED: epilogue reuses wl (weights dead; prebar drains readers),
//   LDS 17.7 KB. PRED: separate mt for h3 (survives restaging), 34.8 KB.
// EPILOGUE: coalesced via LDS transpose (scattered 2B stores = 2x write amp).
template <bool PRED>
__global__ __launch_bounds__(256) void layer_mlp(
    const unsigned short* __restrict__ hin,
    const unsigned short* __restrict__ mean,
    const unsigned short* __restrict__ Wts, const unsigned short* __restrict__ Wtn,
    const float* __restrict__ bias,
    const unsigned short* __restrict__ WtA, const unsigned short* __restrict__ WtB,
    const float* __restrict__ biasA,
    unsigned short* __restrict__ out0, unsigned short* __restrict__ out1, int M) {
  __shared__ unsigned short wl[64][136];             // 17.4 KB weight panel
  __shared__ unsigned short mt[PRED ? 64 : 1][136];  // h3/epilogue tile (PRED only)
  const int tid = threadIdx.x;
  const int lane = tid & 63;
  const int wave = tid >> 6;
  const int m0 = blockIdx.x * 64;
  const int row = lane & 15;
  const int q = lane >> 4;
  const int mw = m0 + wave * 16;
  const int mload = min(mw + row, M - 1);
  const int lrow = wave * 16 + row;  // local row 0..63

  // epilogue transpose tile: PRED -> mt, non-PRED -> wl (weights dead by epilogue)
  unsigned short (*et)[136];
  if constexpr (PRED) et = mt; else et = wl;

  auto stage64 = [&](const unsigned short* W, int half) {
#pragma unroll
    for (int i = 0; i < 4; ++i) {
      int seg = i * 256 + tid;
      int r = seg >> 4, o = (seg & 15) * 8;
      *reinterpret_cast<bf16x8*>(&wl[r][o]) =
          *reinterpret_cast<const bf16x8*>(W + (size_t)(half * 64 + r) * D + o);
    }
  };
  auto mfma_half = [&](bf16x8* a, f32x4* accp) {
#pragma unroll
    for (int s = 0; s < 4; ++s)
#pragma unroll
      for (int t = 0; t < 4; ++t) {
        bf16x8 b = *reinterpret_cast<const bf16x8*>(&wl[t * 16 + row][s * 32 + q * 8]);
        accp[t] = __builtin_amdgcn_mfma_f32_16x16x32_bf16(a[s], b, accp[t], 0, 0, 0);
      }
  };
  // coalesced epilogue: acc (+bias) -> et -> barrier -> contiguous uint4 stores.
  // prebar: barrier BEFORE the et writes (needed when et aliases wl and other
  // waves may still be reading wl in their last mfma_half).
  auto epilogue = [&](f32x4* accp, const float* bvec, unsigned short* dst, bool prebar) {
    if (prebar) __syncthreads();
#pragma unroll
    for (int t = 0; t < 8; ++t) {
      const int col = t * 16 + row;
      const float bv = bvec ? bvec[col] : 0.f;
#pragma unroll
      for (int r = 0; r < 4; ++r)
        et[wave * 16 + q * 4 + r][col] = f32_to_bf16(accp[t][r] + bv);
    }
    __syncthreads();
#pragma unroll
    for (int i = 0; i < 4; ++i) {
      int idx = i * 256 + tid;
      int r2 = idx >> 4;
      int c8 = (idx & 15) * 8;
      int m = m0 + r2;
      if (m < M)
        *reinterpret_cast<uint4*>(dst + (size_t)m * D + c8) =
            *reinterpret_cast<const uint4*>(&et[r2][c8]);
    }
  };

  // ---- stage Ws half 0; A fragments stream in under the staging ----
  stage64(Wts, 0);
  bf16x8 ah[4], am[4];
#pragma unroll
  for (int s = 0; s < 4; ++s) {
    ah[s] = *reinterpret_cast<const bf16x8*>(hin + (size_t)mload * D + s * 32 + q * 8);
    am[s] = *reinterpret_cast<const bf16x8*>(mean + (size_t)mload * D + s * 32 + q * 8);
  }
  __syncthreads();

  f32x4 acc[8];
#pragma unroll
  for (int t = 0; t < 8; ++t) acc[t] = (f32x4){0.f, 0.f, 0.f, 0.f};

  mfma_half(ah, acc);                 // hin @ Ws, n 0..63
  __syncthreads(); stage64(Wts, 1); __syncthreads();
  mfma_half(ah, acc + 4);             // hin @ Ws, n 64..127
  __syncthreads(); stage64(Wtn, 0); __syncthreads();
  mfma_half(am, acc);                 // mean @ Wn, n 0..63
  __syncthreads(); stage64(Wtn, 1); __syncthreads();
  mfma_half(am, acc + 4);             // mean @ Wn, n 64..127

  if (!PRED) {
    epilogue(acc, bias, out0, /*prebar=*/true);  // et = wl: wait for all waves' mfma
    return;
  }

  // ================= PRED tail (layer 3) =================
  __syncthreads();  // all waves done with wl(Wtn half1) before restage
  // ---- h3 (bf16, bias applied) into mt own rows; stage WtA half 0 ----
#pragma unroll
  for (int t = 0; t < 8; ++t) {
    const int col = t * 16 + row;
    const float bv = bias[col];
#pragma unroll
    for (int r = 0; r < 4; ++r)
      mt[wave * 16 + q * 4 + r][col] = f32_to_bf16(acc[t][r] + bv);
  }
  stage64(WtA, 0);
  __syncthreads();
  // ---- h3 A-fragments (each wave reads only rows it wrote) ----
  bf16x8 ap[4];
#pragma unroll
  for (int s = 0; s < 4; ++s)
    ap[s] = *reinterpret_cast<const bf16x8*>(&mt[lrow][s * 32 + q * 8]);

#pragma unroll
  for (int t = 0; t < 8; ++t) acc[t] = (f32x4){0.f, 0.f, 0.f, 0.f};
  mfma_half(ap, acc);                 // h3 @ WtA, n 0..63
  __syncthreads(); stage64(WtA, 1); __syncthreads();
  mfma_half(ap, acc + 4);             // h3 @ WtA, n 64..127
  epilogue(acc, biasA, out0, /*prebar=*/false);  // et = mt, own-row writes safe
  __syncthreads(); stage64(WtB, 0); __syncthreads();
#pragma unroll
  for (int t = 0; t < 8; ++t) acc[t] = (f32x4){0.f, 0.f, 0.f, 0.f};
  mfma_half(ap, acc);                 // h3 @ WtB, n 0..63
  __syncthreads(); stage64(WtB, 1); __syncthreads();
  mfma_half(ap, acc + 4);             // h3 @ WtB, n 64..127
  epilogue(acc, nullptr, out1, /*prebar=*/false);  // epilogue-A reads drained 2 barriers ago
}

// ----------------------------------------------------- edge MLP score, fused pos+neg
// score = relu(A[s]+B[d]).Wp2 + bp2 (bp1 folded into A). One dispatch for both
// edge sets (parity-interleaved groups): measured fused 85.4-86.2us vs split
// 93us. 4 edges / 16-lane group, 8 row-gathers in flight, int4 index loads,
// one coalesced float4 store per group. At the ~3.6 TB/s HBM-side /
// ~7.6 TB/s effective random-gather ceiling (measured invariant across 4
// structural variants; L2-tiling argument says structural for random graph).
__device__ __forceinline__ float relu_dot8(uint4 a, uint4 b, float4 w0, float4 w1) {
  return fmaxf(bf16_lo(a.x) + bf16_lo(b.x), 0.f) * w0.x +
         fmaxf(bf16_hi(a.x) + bf16_hi(b.x), 0.f) * w0.y +
         fmaxf(bf16_lo(a.y) + bf16_lo(b.y), 0.f) * w0.z +
         fmaxf(bf16_hi(a.y) + bf16_hi(b.y), 0.f) * w0.w +
         fmaxf(bf16_lo(a.z) + bf16_lo(b.z), 0.f) * w1.x +
         fmaxf(bf16_hi(a.z) + bf16_hi(b.z), 0.f) * w1.y +
         fmaxf(bf16_lo(a.w) + bf16_lo(b.w), 0.f) * w1.z +
         fmaxf(bf16_hi(a.w) + bf16_hi(b.w), 0.f) * w1.w;
}

__global__ __launch_bounds__(256) void edge_score4(
    const unsigned short* __restrict__ A, const unsigned short* __restrict__ B,
    const int* __restrict__ ps, const int* __restrict__ pd,
    const int* __restrict__ ns, const int* __restrict__ nd,
    const float* __restrict__ Wp2, const float* __restrict__ bp2,
    float* __restrict__ out, int E) {
  const int t = blockIdx.x * blockDim.x + threadIdx.x;
  const int g2 = t >> 4;                // 16 lanes per 4 edges; parity = pos/neg
  const int fl = t & 15;
  const int g = g2 >> 1;
  const int e0 = g * 4;
  if (e0 >= E) return;
  const bool neg = (g2 & 1) != 0;
  const int* ss = neg ? ns : ps;
  const int* dd = neg ? nd : pd;
  float* op = neg ? out + E : out;

  const int4 s4 = *(const int4*)(ss + e0);
  const int4 d4 = *(const int4*)(dd + e0);
  const float4 w0 = *(const float4*)(Wp2 + fl * 8);
  const float4 w1 = *(const float4*)(Wp2 + fl * 8 + 4);
  const size_t fo = (size_t)(fl * 8);

  uint4 a0 = *(const uint4*)(A + (((size_t)s4.x << 7) + fo));
  uint4 b0 = *(const uint4*)(B + (((size_t)d4.x << 7) + fo));
  uint4 a1 = *(const uint4*)(A + (((size_t)s4.y << 7) + fo));
  uint4 b1 = *(const uint4*)(B + (((size_t)d4.y << 7) + fo));
  uint4 a2 = *(const uint4*)(A + (((size_t)s4.z << 7) + fo));
  uint4 b2 = *(const uint4*)(B + (((size_t)d4.z << 7) + fo));
  uint4 a3 = *(const uint4*)(A + (((size_t)s4.w << 7) + fo));
  uint4 b3 = *(const uint4*)(B + (((size_t)d4.w << 7) + fo));

  float p0 = relu_dot8(a0, b0, w0, w1);
  float p1 = relu_dot8(a1, b1, w0, w1);
  float p2 = relu_dot8(a2, b2, w0, w1);
  float p3 = relu_dot8(a3, b3, w0, w1);

  p0 += __shfl_xor(p0, 1); p1 += __shfl_xor(p1, 1); p2 += __shfl_xor(p2, 1); p3 += __shfl_xor(p3, 1);
  p0 += __shfl_xor(p0, 2); p1 += __shfl_xor(p1, 2); p2 += __shfl_xor(p2, 2); p3 += __shfl_xor(p3, 2);
  p0 += __shfl_xor(p0, 4); p1 += __shfl_xor(p1, 4); p2 += __shfl_xor(p2, 4); p3 += __shfl_xor(p3, 4);
  p0 += __shfl_xor(p0, 8); p1 += __shfl_xor(p1, 8); p2 += __shfl_xor(p2, 8); p3 += __shfl_xor(p3, 8);

  if (fl == 0) {
    const float bv = bp2[0];
    *reinterpret_cast<float4*>(op + e0) = make_float4(p0 + bv, p1 + bv, p2 + bv, p3 + bv);
  }
}

// ---------------------------------------------------------------- launcher
extern "C" void kernel_launch(void* const* d_in, const int* in_sizes, int n_in,
                              void* d_out, int out_size, void* d_ws, size_t ws_size,
                              hipStream_t stream) {
  const float* x = (const float*)d_in[0];
  const int* src = (const int*)d_in[1];
  const int* dst = (const int*)d_in[2];
  const int* nsrc = (const int*)d_in[3];
  const int* ndst = (const int*)d_in[4];
  const float* Ws1 = (const float*)d_in[5];
  const float* Wn1 = (const float*)d_in[6];
  const float* b1 = (const float*)d_in[7];
  const float* Ws2 = (const float*)d_in[8];
  const float* Wn2 = (const float*)d_in[9];
  const float* b2 = (const float*)d_in[10];
  const float* Ws3 = (const float*)d_in[11];
  const float* Wn3 = (const float*)d_in[12];
  const float* b3 = (const float*)d_in[13];
  const float* Wp1 = (const float*)d_in[14];
  const float* bp1 = (const float*)d_in[15];
  const float* Wp2 = (const float*)d_in[16];
  const float* bp2 = (const float*)d_in[17];
  float* out = (float*)d_out;

  char* ws = (char*)d_ws;
  size_t off = 0;
  auto alloc = [&](size_t bytes) -> void* {
    void* p = ws + off;
    off += (bytes + 255) & ~(size_t)255;
    return p;
  };
  const size_t NODE_F32 = sizeof(float) * (size_t)N_NODES * D;  // 51.2 MB
  char* region0 = (char*)alloc(NODE_F32);   // bf16 xb | (spare) -> later bf16 Ab | Bb
  char* region1 = (char*)alloc(NODE_F32);   // bf16 hA | hB
  unsigned short* meanb = (unsigned short*)alloc(sizeof(unsigned short) * (size_t)N_NODES * D);
  int* row_start = (int*)alloc(sizeof(int) * (N_NODES + 1));
  int* deg = (int*)alloc(sizeof(int) * N_NODES * 2);  // deg + cursor
  int* cursor = deg + N_NODES;
  int* esrc = (int*)alloc(sizeof(int) * N_EDGES);
  int* partial = (int*)alloc(sizeof(int) * 128);
  unsigned short* wt = (unsigned short*)alloc(sizeof(unsigned short) * 8 * D * D);
  (void)ws_size;

  unsigned short* xb = (unsigned short*)region0;
  unsigned short* hA = (unsigned short*)region1;
  unsigned short* hB = hA + (size_t)N_NODES * D;
  unsigned short* Ab = xb;                              // xb dead after layer-1 MLP
  unsigned short* Bb = xb + (size_t)N_NODES * D;        // second half of region0

  // ---- conversions
  f32_to_bf16_vec<<<(N_NODES * D / 4 + 255) / 256, 256, 0, stream>>>(x, xb, N_NODES * D / 4);
  transpose_w<<<512, 256, 0, stream>>>(Ws1, Wn1, Ws2, Wn2, Ws3, Wn3, Wp1, Wp1 + D * D, wt);

  // ---- CSR build (pos edges; reused by all 3 layers)
  zero_i32<<<(2 * N_NODES + 255) / 256, 256, 0, stream>>>(deg, 2 * N_NODES);
  hist_kernel<<<(N_EDGES + 255) / 256, 256, 0, stream>>>(dst, deg, N_EDGES);
  scan_blocksum<<<SCAN_BLOCKS, 256, 0, stream>>>(deg, partial, N_NODES);
  scan_offsets<<<1, 128, 0, stream>>>(partial, row_start, SCAN_BLOCKS, N_NODES);
  scan_final<<<SCAN_BLOCKS, 256, 0, stream>>>(deg, partial, row_start, N_NODES);
  fill_kernel<<<(N_EDGES + 255) / 256, 256, 0, stream>>>(src, dst, row_start, cursor, esrc, N_EDGES);

  const int gatherBlocks = (N_NODES * 16 + 255) / 256;    // 6250
  const int mlpBlocks = (N_NODES + 63) / 64;              // 1563
  const int edgeBlocks = (2 * (N_EDGES / 4) * 16) / 256;  // 20000 (pos+neg fused)

  // ---- layer 1
  gather_mean<<<gatherBlocks, 256, 0, stream>>>(xb, row_start, esrc, meanb, N_NODES);
  layer_mlp<false><<<mlpBlocks, 256, 0, stream>>>(
      xb, meanb, wt, wt + 16384, b1, nullptr, nullptr, nullptr, hA, nullptr, N_NODES);
  // ---- layer 2
  gather_mean<<<gatherBlocks, 256, 0, stream>>>(hA, row_start, esrc, meanb, N_NODES);
  layer_mlp<false><<<mlpBlocks, 256, 0, stream>>>(
      hA, meanb, wt + 2 * 16384, wt + 3 * 16384, b2, nullptr, nullptr, nullptr, hB, nullptr, N_NODES);
  // ---- layer 3 + predictor
  gather_mean<<<gatherBlocks, 256, 0, stream>>>(hB, row_start, esrc, meanb, N_NODES);
  layer_mlp<true><<<mlpBlocks, 256, 0, stream>>>(
      hB, meanb, wt + 4 * 16384, wt + 5 * 16384, b3, wt + 6 * 16384, wt + 7 * 16384, bp1,
      Ab, Bb, N_NODES);
  // ---- edge scores: pos+neg in one dispatch (disjoint outputs)
  edge_score4<<<edgeBlocks, 256, 0, stream>>>(Ab, Bb, src, dst, nsrc, ndst, Wp2, bp2, out, N_EDGES);
}